// Round 15
// baseline (156.695 us; speedup 1.0000x reference)
//
#include <hip/hip_runtime.h>
#include <hip/hip_bf16.h>
#include <stdint.h>
#include <math.h>

// Problem constants (from reference): B=4096, D=768, N=8192, S=4
#define Bdim 4096
#define Ddim 768
#define Ndim 8192
#define Sdim 4

typedef __attribute__((ext_vector_type(4))) float floatx4;
typedef __attribute__((ext_vector_type(8))) int int8v;
typedef __attribute__((ext_vector_type(4))) int int4v;

// pack float4 -> 4x fp8 e4m3 (OCP on gfx950), HW RNE
__device__ inline int pack_fp8x4(float4 v) {
  int r = __builtin_amdgcn_cvt_pk_fp8_f32(v.x, v.y, 0, 0);  // low word
  r = __builtin_amdgcn_cvt_pk_fp8_f32(v.z, v.w, r, 1);      // high word
  return r;
}

// ---------------------------------------------------------------------------
// Kernel 1: fp32 -> fp8 e4m3 quantization of batch_x and cat; zero the stats
// region; theta[s,b] = exp(batch_x[b].phi[s]) in fp32 (one wave per b).
// R16: theta dot product via float4 loads. (pinned since)
// stats = [s4 (B) | denom (B) | numer (S*B)] floats
// ---------------------------------------------------------------------------
__global__ void convert_kernel(const float* __restrict__ x,
                               const float* __restrict__ cat,
                               const float* __restrict__ phi,
                               unsigned char* __restrict__ xq,
                               unsigned char* __restrict__ catq,
                               float* __restrict__ stats,
                               float* __restrict__ theta) {
  int gid = blockIdx.x * blockDim.x + threadIdx.x;
  int stride = gridDim.x * blockDim.x;
  const int nx4 = (Bdim * Ddim) / 4;
  const int nc4 = (Ndim * Ddim) / 4;
  for (int i = gid; i < nx4; i += stride)
    ((int*)xq)[i] = pack_fp8x4(((const float4*)x)[i]);
  for (int i = gid; i < nc4; i += stride)
    ((int*)catq)[i] = pack_fp8x4(((const float4*)cat)[i]);
  if (gid < 6 * Bdim) stats[gid] = 0.0f;

  // theta: one wave per batch row (fp32 — exact path, output-critical)
  int gw = gid >> 6;
  int lane = threadIdx.x & 63;
  if (gw < Bdim) {
    const float4* xr4 = (const float4*)(x + (size_t)gw * Ddim);
    const float4* ph4 = (const float4*)phi;
    const int D4 = Ddim / 4;  // 192
    float a0 = 0.f, a1 = 0.f, a2 = 0.f, a3 = 0.f;
#pragma unroll
    for (int d4 = lane; d4 < D4; d4 += 64) {
      float4 xv = xr4[d4];
      float4 p0 = ph4[d4];
      float4 p1 = ph4[D4 + d4];
      float4 p2 = ph4[2 * D4 + d4];
      float4 p3 = ph4[3 * D4 + d4];
      a0 = fmaf(xv.x, p0.x, fmaf(xv.y, p0.y, fmaf(xv.z, p0.z, fmaf(xv.w, p0.w, a0))));
      a1 = fmaf(xv.x, p1.x, fmaf(xv.y, p1.y, fmaf(xv.z, p1.z, fmaf(xv.w, p1.w, a1))));
      a2 = fmaf(xv.x, p2.x, fmaf(xv.y, p2.y, fmaf(xv.z, p2.z, fmaf(xv.w, p2.w, a2))));
      a3 = fmaf(xv.x, p3.x, fmaf(xv.y, p3.y, fmaf(xv.z, p3.z, fmaf(xv.w, p3.w, a3))));
    }
#pragma unroll
    for (int off = 32; off > 0; off >>= 1) {
      a0 += __shfl_down(a0, off);
      a1 += __shfl_down(a1, off);
      a2 += __shfl_down(a2, off);
      a3 += __shfl_down(a3, off);
    }
    if (lane == 0) {
      theta[gw] = __expf(a0);
      theta[Bdim + gw] = __expf(a1);
      theta[2 * Bdim + gw] = __expf(a2);
      theta[3 * Bdim + gw] = __expf(a3);
    }
  }
}

// ---------------------------------------------------------------------------
// Kernel 2: MX-scaled fp8 MFMA GEMM  con[n,b] = sum_k cat[n,k]*x[b,k]
// R20: REVERT to R13's REGISTER-PREFETCH pipeline — the measured-best GEMM.
// Ledger: R13 reg-staged = 52.2us (155.8 - R14's 103.6 non-GEMM);
// R17/R19 gl_lds single-buf = 58.9us; R14 gl_lds dbuf = 66.6; R18 = spill.
// Mechanism: reg-staging issues tile k+1's 8 global_load_dwordx4 BEFORE
// compute of tile k -> HBM latency (~900cy) hides under compute+ds_reads
// (T14 issue-early). gl_lds + single buffer cannot issue until the buffer
// frees -> latency exposed per iter, only partly covered at 3 blocks/CU.
// Structure (R13-exact, verified at 155.8): single 16KB As/Bs, granule-
// interleaved slot = (r>>3)*64 + g*8 + (r&7); prefetch next tile to VGPRs
// during compute; read-barrier; ds_write_b128 regs -> LDS; write-barrier.
// Fragment k = quad*32+j; unit E8M0 scales; con fp8 [N/4,B,4] packed dword;
// pow4 on fp32 acc. Bank conflicts ~3.1M (~5us) known; swizzle is the next
// experiment if this lands as predicted.
// ---------------------------------------------------------------------------
__global__ __launch_bounds__(256) void gemm_bt_kernel(
    const unsigned char* __restrict__ A,    // cat fp8 [Ndim, Ddim]
    const unsigned char* __restrict__ Bm,   // x   fp8 [Bdim, Ddim]
    unsigned int* __restrict__ Cw,          // con fp8 [Ndim/4, Bdim, 4] as u32
    float* __restrict__ s4) {               // [Bdim] p4 column sums
  __shared__ unsigned char As[128 * 128];  // 16 KB, granule-interleaved
  __shared__ unsigned char Bs[128 * 128];  // 16 KB

  const int tid = threadIdx.x;
  const int wave = tid >> 6;
  const int lane = tid & 63;
  const int quad = lane >> 4;
  const int l16 = lane & 15;
  const int wm = (wave & 1) * 64;
  const int wn = (wave >> 1) * 64;
  const int m0 = blockIdx.x * 128;
  const int n0 = blockIdx.y * 128;

  floatx4 acc[4][4];
#pragma unroll
  for (int i = 0; i < 4; ++i)
#pragma unroll
    for (int j = 0; j < 4; ++j) acc[i][j] = (floatx4){0.f, 0.f, 0.f, 0.f};

  // staging: 1024 granule-slots per operand per K-tile; slot p holds
  // (row = (p>>6)*8 + (p&7), granule g = (p>>3)&7); 4 slots per thread.
  const unsigned char* a_src[4];
  const unsigned char* b_src[4];
#pragma unroll
  for (int i = 0; i < 4; ++i) {
    int p = tid + 256 * i;
    int row = ((p >> 6) << 3) + (p & 7);
    int colb = ((p >> 3) & 7) * 16;
    a_src[i] = A + (size_t)(m0 + row) * Ddim + colb;
    b_src[i] = Bm + (size_t)(n0 + row) * Ddim + colb;
  }

  // prologue: tile 0 -> regs -> LDS (latency exposed once, not per-iter)
  int4v areg[4], breg[4];
#pragma unroll
  for (int i = 0; i < 4; ++i) {
    areg[i] = *(const int4v*)(a_src[i]);
    breg[i] = *(const int4v*)(b_src[i]);
  }
#pragma unroll
  for (int i = 0; i < 4; ++i) {
    *(int4v*)(As + (tid + 256 * i) * 16) = areg[i];
    *(int4v*)(Bs + (tid + 256 * i) * 16) = breg[i];
  }
  __syncthreads();

  for (int kk = 0; kk < 6; ++kk) {
    if (kk < 5) {
      const int k0 = (kk + 1) * 128;
      // prefetch next tile into VGPRs; whole compute phase hides latency
#pragma unroll
      for (int i = 0; i < 4; ++i) {
        areg[i] = *(const int4v*)(a_src[i] + k0);
        breg[i] = *(const int4v*)(b_src[i] + k0);
      }
    }

    // compute current tile from LDS.
    // fragment: row r, k = quad*32..+31 = granules 2q,2q+1 ->
    // byte (r>>3)*1024 + quad*256 + (r&7)*16, and +128.
    int8v af[4], bf[4];
#pragma unroll
    for (int mi = 0; mi < 4; ++mi) {
      int r = wm + mi * 16 + l16;
      int base = ((r >> 3) << 10) + quad * 256 + (r & 7) * 16;
      int4v lo = *(const int4v*)(As + base);
      int4v hi = *(const int4v*)(As + base + 128);
      af[mi] = __builtin_shufflevector(lo, hi, 0, 1, 2, 3, 4, 5, 6, 7);
    }
#pragma unroll
    for (int ni = 0; ni < 4; ++ni) {
      int r = wn + ni * 16 + l16;
      int base = ((r >> 3) << 10) + quad * 256 + (r & 7) * 16;
      int4v lo = *(const int4v*)(Bs + base);
      int4v hi = *(const int4v*)(Bs + base + 128);
      bf[ni] = __builtin_shufflevector(lo, hi, 0, 1, 2, 3, 4, 5, 6, 7);
    }
#pragma unroll
    for (int mi = 0; mi < 4; ++mi)
#pragma unroll
      for (int ni = 0; ni < 4; ++ni)
        acc[mi][ni] = __builtin_amdgcn_mfma_scale_f32_16x16x128_f8f6f4(
            af[mi], bf[ni], acc[mi][ni], 0, 0,  // cbsz=0 (fp8), blgp=0 (fp8)
            0, 0x7f7f7f7f,                      // scale A: E8M0 1.0
            0, 0x7f7f7f7f);                     // scale B: E8M0 1.0

    __syncthreads();  // all reads of the tile done (residual vmcnt drain)

    if (kk < 5) {
#pragma unroll
      for (int i = 0; i < 4; ++i) {
        *(int4v*)(As + (tid + 256 * i) * 16) = areg[i];
        *(int4v*)(Bs + (tid + 256 * i) * 16) = breg[i];
      }
      __syncthreads();  // LDS ready for next iter
    }
  }

  // C/D layout (16x16): col = lane&15, row = quad*4 + reg [verified].
  // acc[..][0..3] = rows 4g..4g+3 of one column -> one packed u32 at
  // word index g*Bdim + col of the [N/4, B, 4] layout.
  float cs4[4] = {0.f, 0.f, 0.f, 0.f};
#pragma unroll
  for (int mi = 0; mi < 4; ++mi)
#pragma unroll
    for (int ni = 0; ni < 4; ++ni) {
      int g = (m0 + wm + mi * 16) / 4 + quad;  // n-group index
      int col = n0 + wn + ni * 16 + l16;
      floatx4 a = acc[mi][ni];
      int w = __builtin_amdgcn_cvt_pk_fp8_f32(a[0], a[1], 0, 0);
      w = __builtin_amdgcn_cvt_pk_fp8_f32(a[2], a[3], w, 1);
      Cw[(size_t)g * Bdim + col] = (unsigned int)w;
#pragma unroll
      for (int rr = 0; rr < 4; ++rr) {
        float c2 = a[rr] * a[rr];
        cs4[ni] += c2 * c2;  // pow4 on exact fp32 acc
      }
    }
#pragma unroll
  for (int ni = 0; ni < 4; ++ni) {
    float v = cs4[ni];
    v += __shfl_xor(v, 16);
    v += __shfl_xor(v, 32);
    if (quad == 0) atomicAdd(&s4[n0 + wn + ni * 16 + l16], v);
  }
}

// ---------------------------------------------------------------------------
// Kernel 3: denom[b] += sum exp(con/norm4); numer[s,b] += y-masked sum.
// Reads fp8 [N/4, B, 4] con: one u32 = 4 n-elements per thread per iter,
// lanes on consecutive b -> 256B/wave coalesced; y via wave-uniform int4.
// norm4 >= max|fp32 con| -> no max-subtraction needed. 2 atomics/thread.
// R15: log2(e) folded into scale; exp2f native v_exp_f32.
// R18 MEASURED: (16,128) 8 blocks/CU cut non-GEMM 103.0 -> 95.5us — kept.
// ---------------------------------------------------------------------------
__global__ void expsum_kernel(const unsigned int* __restrict__ conq,
                              const float* __restrict__ s4,
                              const int* __restrict__ y,
                              float* __restrict__ denom,
                              float* __restrict__ numer) {
  int b = blockIdx.x * 256 + threadIdx.x;
  int g0 = blockIdx.y * 16;                 // n-group range [g0, g0+16)
  int src = (g0 * 4) / (Ndim / Sdim);       // uniform per block

  float inv = 1.0f / fmaxf(sqrtf(sqrtf(s4[b])), 1e-12f);
  float inv2 = inv * 1.4426950408889634f;   // fold ln2 conversion into scale
  const unsigned int* p = conq + (size_t)g0 * Bdim + b;
  float dsum = 0.f, nsum = 0.f;
#pragma unroll 4
  for (int i = 0; i < 16; ++i) {
    unsigned int w = p[(size_t)i * Bdim];
    int4 yv = *(const int4*)(y + 4 * (g0 + i));  // wave-uniform
    float e0 = exp2f(__builtin_amdgcn_cvt_f32_fp8(w, 0) * inv2);
    float e1 = exp2f(__builtin_amdgcn_cvt_f32_fp8(w, 1) * inv2);
    float e2 = exp2f(__builtin_amdgcn_cvt_f32_fp8(w, 2) * inv2);
    float e3 = exp2f(__builtin_amdgcn_cvt_f32_fp8(w, 3) * inv2);
    dsum += e0 + e1 + e2 + e3;
    nsum += e0 * (float)yv.x + e1 * (float)yv.y + e2 * (float)yv.z +
            e3 * (float)yv.w;
  }
  atomicAdd(&denom[b], dsum);
  atomicAdd(&numer[src * Bdim + b], nsum);
}

// ---------------------------------------------------------------------------
// Kernel 4 (tiny): out[b] = sigmoid(sum_s numer[s,b]*theta[s,b]/denom[b]+bias)
// ---------------------------------------------------------------------------
__global__ void finalize_kernel(const float* __restrict__ denom,
                                const float* __restrict__ numer,
                                const float* __restrict__ theta,
                                const float* __restrict__ bias,
                                float* __restrict__ out) {
  int b = blockIdx.x * 256 + threadIdx.x;
  float acc = 0.f;
#pragma unroll
  for (int si = 0; si < Sdim; ++si)
    acc += numer[si * Bdim + b] * theta[si * Bdim + b];
  float z = acc / denom[b] + bias[0];
  out[b] = 1.0f / (1.0f + __expf(-z));
}

// ---------------------------------------------------------------------------
// Workspace layout (bytes):
//   catq  : Ndim*Ddim     =  6,291,456   (fp8)
//   xq    : Bdim*Ddim     =  3,145,728   (fp8)
//   conq  : Ndim*Bdim     = 33,554,432   (fp8, [N/4, B, 4] interleaved)
//   stats : 6*Bdim*4      =     98,304   (s4 | denom | numer)
//   theta : Sdim*Bdim*4   =     65,536
//   total ≈ 43.2 MB
// Session ledger (GEMM µs): R13 reg-staged 52.2 | R14 gl_lds dbuf 66.6 |
// R16 bounds-spill 161 | R17/R19 gl_lds single 58.9 | R18 bounds-spill 79.6.
// Non-GEMM: 103.6 -> 95.5 (expsum 8blk/CU); ~75us of it is fixed overhead.
// ---------------------------------------------------------------------------
extern "C" void kernel_launch(void* const* d_in, const int* in_sizes, int n_in,
                              void* d_out, int out_size, void* d_ws,
                              size_t ws_size, hipStream_t stream) {
  const float* batch_x = (const float*)d_in[0];
  const float* cat = (const float*)d_in[1];
  const int* y = (const int*)d_in[2];
  const float* phi = (const float*)d_in[3];
  const float* bias = (const float*)d_in[4];
  float* out = (float*)d_out;

  char* ws = (char*)d_ws;
  unsigned char* catq = (unsigned char*)ws;
  unsigned char* xq = catq + (size_t)Ndim * Ddim;
  unsigned int* conq = (unsigned int*)(xq + (size_t)Bdim * Ddim);
  float* stats = (float*)((unsigned char*)conq + (size_t)Ndim * Bdim);
  float* s4 = stats;
  float* denom = s4 + Bdim;
  float* numer = denom + Bdim;        // Sdim * Bdim
  float* theta = stats + 6 * Bdim;    // Sdim * Bdim

  convert_kernel<<<2048, 256, 0, stream>>>(batch_x, cat, phi, xq, catq, stats,
                                           theta);

  dim3 g2(Ndim / 128, Bdim / 128);
  gemm_bt_kernel<<<g2, 256, 0, stream>>>(catq, xq, conq, s4);

  dim3 g3(Bdim / 256, 128);
  expsum_kernel<<<g3, 256, 0, stream>>>(conq, s4, y, denom, numer);

  finalize_kernel<<<Bdim / 256, 256, 0, stream>>>(denom, numer, theta, bias,
                                                  out);
}

// Round 16
// 154.206 us; speedup vs baseline: 1.0161x; 1.0161x over previous
//
#include <hip/hip_runtime.h>
#include <hip/hip_bf16.h>
#include <stdint.h>
#include <math.h>

// Problem constants (from reference): B=4096, D=768, N=8192, S=4
#define Bdim 4096
#define Ddim 768
#define Ndim 8192
#define Sdim 4

typedef __attribute__((ext_vector_type(4))) float floatx4;
typedef __attribute__((ext_vector_type(8))) int int8v;
typedef __attribute__((ext_vector_type(4))) int int4v;

// pack float4 -> 4x fp8 e4m3 (OCP on gfx950), HW RNE
__device__ inline int pack_fp8x4(float4 v) {
  int r = __builtin_amdgcn_cvt_pk_fp8_f32(v.x, v.y, 0, 0);  // low word
  r = __builtin_amdgcn_cvt_pk_fp8_f32(v.z, v.w, r, 1);      // high word
  return r;
}

// async global->LDS direct copy, 16B per lane. HW semantics: LDS dest =
// wave-uniform base + lane*16 (m104); global src is per-lane.
__device__ __forceinline__ void gl_lds16(const void* g, void* lds_base) {
  __builtin_amdgcn_global_load_lds(
      (const __attribute__((address_space(1))) unsigned int*)g,
      (__attribute__((address_space(3))) unsigned int*)lds_base, 16, 0, 0);
}

// ---------------------------------------------------------------------------
// Kernel 1: fp32 -> fp8 e4m3 quantization of batch_x and cat; zero the stats
// region; theta[s,b] = exp(batch_x[b].phi[s]) in fp32 (one wave per b).
// R16: theta dot product via float4 loads. (pinned)
// stats = [s4 (B) | denom (B) | numer (S*B)] floats
// ---------------------------------------------------------------------------
__global__ void convert_kernel(const float* __restrict__ x,
                               const float* __restrict__ cat,
                               const float* __restrict__ phi,
                               unsigned char* __restrict__ xq,
                               unsigned char* __restrict__ catq,
                               float* __restrict__ stats,
                               float* __restrict__ theta) {
  int gid = blockIdx.x * blockDim.x + threadIdx.x;
  int stride = gridDim.x * blockDim.x;
  const int nx4 = (Bdim * Ddim) / 4;
  const int nc4 = (Ndim * Ddim) / 4;
  for (int i = gid; i < nx4; i += stride)
    ((int*)xq)[i] = pack_fp8x4(((const float4*)x)[i]);
  for (int i = gid; i < nc4; i += stride)
    ((int*)catq)[i] = pack_fp8x4(((const float4*)cat)[i]);
  if (gid < 6 * Bdim) stats[gid] = 0.0f;

  // theta: one wave per batch row (fp32 — exact path, output-critical)
  int gw = gid >> 6;
  int lane = threadIdx.x & 63;
  if (gw < Bdim) {
    const float4* xr4 = (const float4*)(x + (size_t)gw * Ddim);
    const float4* ph4 = (const float4*)phi;
    const int D4 = Ddim / 4;  // 192
    float a0 = 0.f, a1 = 0.f, a2 = 0.f, a3 = 0.f;
#pragma unroll
    for (int d4 = lane; d4 < D4; d4 += 64) {
      float4 xv = xr4[d4];
      float4 p0 = ph4[d4];
      float4 p1 = ph4[D4 + d4];
      float4 p2 = ph4[2 * D4 + d4];
      float4 p3 = ph4[3 * D4 + d4];
      a0 = fmaf(xv.x, p0.x, fmaf(xv.y, p0.y, fmaf(xv.z, p0.z, fmaf(xv.w, p0.w, a0))));
      a1 = fmaf(xv.x, p1.x, fmaf(xv.y, p1.y, fmaf(xv.z, p1.z, fmaf(xv.w, p1.w, a1))));
      a2 = fmaf(xv.x, p2.x, fmaf(xv.y, p2.y, fmaf(xv.z, p2.z, fmaf(xv.w, p2.w, a2))));
      a3 = fmaf(xv.x, p3.x, fmaf(xv.y, p3.y, fmaf(xv.z, p3.z, fmaf(xv.w, p3.w, a3))));
    }
#pragma unroll
    for (int off = 32; off > 0; off >>= 1) {
      a0 += __shfl_down(a0, off);
      a1 += __shfl_down(a1, off);
      a2 += __shfl_down(a2, off);
      a3 += __shfl_down(a3, off);
    }
    if (lane == 0) {
      theta[gw] = __expf(a0);
      theta[Bdim + gw] = __expf(a1);
      theta[2 * Bdim + gw] = __expf(a2);
      theta[3 * Bdim + gw] = __expf(a3);
    }
  }
}

// ---------------------------------------------------------------------------
// Kernel 2: MX-scaled fp8 MFMA GEMM  con[n,b] = sum_k cat[n,k]*x[b,k]
// R21 = R19 (SESSION BEST, 155.46us total, GEMM 58.9us): gl_lds staging,
// single 32KB LDS, 2 barriers/iter, plain __launch_bounds__(256).
// Staging-fork ledger (all measured): gl_lds single-buf 58.9 ≈ reg-prefetch
// 59.2 (R20 falsified the 52.2 cross-round estimate — rule #13) <
// gl_lds dbuf 66.6 (R14) < bounds-spill 79.6/161 (R18/R16).
// Structural ceiling: 886 TF = the 2-barrier 128^2 schedule (m97-class);
// per-iter ~8.8K cy vs ~550 cy MFMA — barrier-drain dominated; T2/T5/staging
// swaps all measured-null in this regime (guide regime-gate, m230/m233).
// Known escape = 8-phase 256^2 counted-vmcnt port (m201): est. 59->45us,
// high race risk (m152) — not attempted blind.
// Verified pieces: linear-in-tid LDS dest + granule interleave in per-lane
// SOURCE pointers (m173); fragment k = quad*32+j; unit E8M0 scales; con fp8
// [N/4, B, 4] packed dword; pow4 on fp32 acc. Bank conflicts 3.1M ≈ inherent
// 4-way b128 aliasing (not swizzle-fixable; redistribution can't beat the
// 8-access/bank floor of 1KB/instruction reads).
// ---------------------------------------------------------------------------
__global__ __launch_bounds__(256) void gemm_bt_kernel(
    const unsigned char* __restrict__ A,    // cat fp8 [Ndim, Ddim]
    const unsigned char* __restrict__ Bm,   // x   fp8 [Bdim, Ddim]
    unsigned int* __restrict__ Cw,          // con fp8 [Ndim/4, Bdim, 4] as u32
    float* __restrict__ s4) {               // [Bdim] p4 column sums
  __shared__ unsigned char As[128 * 128];  // 16 KB, granule-interleaved
  __shared__ unsigned char Bs[128 * 128];  // 16 KB

  const int tid = threadIdx.x;
  const int wave = tid >> 6;
  const int lane = tid & 63;
  const int quad = lane >> 4;
  const int l16 = lane & 15;
  const int wm = (wave & 1) * 64;
  const int wn = (wave >> 1) * 64;
  const int m0 = blockIdx.x * 128;
  const int n0 = blockIdx.y * 128;

  floatx4 acc[4][4];
#pragma unroll
  for (int i = 0; i < 4; ++i)
#pragma unroll
    for (int j = 0; j < 4; ++j) acc[i][j] = (floatx4){0.f, 0.f, 0.f, 0.f};

  // staging: 1024 granule-slots per operand per K-tile; slot p holds
  // (row = (p>>6)*8 + (p&7), granule g = (p>>3)&7); 4 slots per thread.
  // LDS dest for issue i, wave w: uniform base (w*64 + 256*i)*16, HW adds
  // lane*16 -> slot p = tid + 256*i.
  const unsigned char* a_src[4];
  const unsigned char* b_src[4];
#pragma unroll
  for (int i = 0; i < 4; ++i) {
    int p = tid + 256 * i;
    int row = ((p >> 6) << 3) + (p & 7);
    int colb = ((p >> 3) & 7) * 16;
    a_src[i] = A + (size_t)(m0 + row) * Ddim + colb;
    b_src[i] = Bm + (size_t)(n0 + row) * Ddim + colb;
  }
  const int wbase = (wave * 64) * 16;  // wave-uniform LDS byte base (i=0)

  // prologue: tile 0 async -> LDS
#pragma unroll
  for (int i = 0; i < 4; ++i) {
    gl_lds16(a_src[i], &As[wbase + i * 4096]);
    gl_lds16(b_src[i], &Bs[wbase + i * 4096]);
  }
  __syncthreads();  // vmcnt(0) drain: tile 0 resident

  for (int kk = 0; kk < 6; ++kk) {
    // compute current tile from LDS.
    // fragment: row r, k = quad*32..+31 = granules 2q,2q+1 ->
    // byte (r>>3)*1024 + quad*256 + (r&7)*16, and +128.
    int8v af[4], bf[4];
#pragma unroll
    for (int mi = 0; mi < 4; ++mi) {
      int r = wm + mi * 16 + l16;
      int base = ((r >> 3) << 10) + quad * 256 + (r & 7) * 16;
      int4v lo = *(const int4v*)(&As[base]);
      int4v hi = *(const int4v*)(&As[base + 128]);
      af[mi] = __builtin_shufflevector(lo, hi, 0, 1, 2, 3, 4, 5, 6, 7);
    }
#pragma unroll
    for (int ni = 0; ni < 4; ++ni) {
      int r = wn + ni * 16 + l16;
      int base = ((r >> 3) << 10) + quad * 256 + (r & 7) * 16;
      int4v lo = *(const int4v*)(&Bs[base]);
      int4v hi = *(const int4v*)(&Bs[base + 128]);
      bf[ni] = __builtin_shufflevector(lo, hi, 0, 1, 2, 3, 4, 5, 6, 7);
    }
#pragma unroll
    for (int mi = 0; mi < 4; ++mi)
#pragma unroll
      for (int ni = 0; ni < 4; ++ni)
        acc[mi][ni] = __builtin_amdgcn_mfma_scale_f32_16x16x128_f8f6f4(
            af[mi], bf[ni], acc[mi][ni], 0, 0,  // cbsz=0 (fp8), blgp=0 (fp8)
            0, 0x7f7f7f7f,                      // scale A: E8M0 1.0
            0, 0x7f7f7f7f);                     // scale B: E8M0 1.0

    __syncthreads();  // all waves done reading the tile

    if (kk < 5) {
      const int k0 = (kk + 1) * 128;
#pragma unroll
      for (int i = 0; i < 4; ++i) {
        gl_lds16(a_src[i] + k0, &As[wbase + i * 4096]);
        gl_lds16(b_src[i] + k0, &Bs[wbase + i * 4096]);
      }
      __syncthreads();  // vmcnt(0) drain: next tile resident
      // (drain exposed per-block; covered by co-resident blocks, m114)
    }
  }

  // C/D layout (16x16): col = lane&15, row = quad*4 + reg [verified].
  // acc[..][0..3] = rows 4g..4g+3 of one column -> one packed u32 at
  // word index g*Bdim + col of the [N/4, B, 4] layout.
  float cs4[4] = {0.f, 0.f, 0.f, 0.f};
#pragma unroll
  for (int mi = 0; mi < 4; ++mi)
#pragma unroll
    for (int ni = 0; ni < 4; ++ni) {
      int g = (m0 + wm + mi * 16) / 4 + quad;  // n-group index
      int col = n0 + wn + ni * 16 + l16;
      floatx4 a = acc[mi][ni];
      int w = __builtin_amdgcn_cvt_pk_fp8_f32(a[0], a[1], 0, 0);
      w = __builtin_amdgcn_cvt_pk_fp8_f32(a[2], a[3], w, 1);
      Cw[(size_t)g * Bdim + col] = (unsigned int)w;
#pragma unroll
      for (int rr = 0; rr < 4; ++rr) {
        float c2 = a[rr] * a[rr];
        cs4[ni] += c2 * c2;  // pow4 on exact fp32 acc
      }
    }
#pragma unroll
  for (int ni = 0; ni < 4; ++ni) {
    float v = cs4[ni];
    v += __shfl_xor(v, 16);
    v += __shfl_xor(v, 32);
    if (quad == 0) atomicAdd(&s4[n0 + wn + ni * 16 + l16], v);
  }
}

// ---------------------------------------------------------------------------
// Kernel 3: denom[b] += sum exp(con/norm4); numer[s,b] += y-masked sum.
// Reads fp8 [N/4, B, 4] con: one u32 = 4 n-elements per thread per iter,
// lanes on consecutive b -> 256B/wave coalesced; y via wave-uniform int4.
// norm4 >= max|fp32 con| -> no max-subtraction needed. 2 atomics/thread.
// R15: log2(e) folded into scale; exp2f native v_exp_f32.
// R18 MEASURED: (16,128) 8 blocks/CU cut non-GEMM 103.0 -> 95.5us — kept.
// ---------------------------------------------------------------------------
__global__ void expsum_kernel(const unsigned int* __restrict__ conq,
                              const float* __restrict__ s4,
                              const int* __restrict__ y,
                              float* __restrict__ denom,
                              float* __restrict__ numer) {
  int b = blockIdx.x * 256 + threadIdx.x;
  int g0 = blockIdx.y * 16;                 // n-group range [g0, g0+16)
  int src = (g0 * 4) / (Ndim / Sdim);       // uniform per block

  float inv = 1.0f / fmaxf(sqrtf(sqrtf(s4[b])), 1e-12f);
  float inv2 = inv * 1.4426950408889634f;   // fold ln2 conversion into scale
  const unsigned int* p = conq + (size_t)g0 * Bdim + b;
  float dsum = 0.f, nsum = 0.f;
#pragma unroll 4
  for (int i = 0; i < 16; ++i) {
    unsigned int w = p[(size_t)i * Bdim];
    int4 yv = *(const int4*)(y + 4 * (g0 + i));  // wave-uniform
    float e0 = exp2f(__builtin_amdgcn_cvt_f32_fp8(w, 0) * inv2);
    float e1 = exp2f(__builtin_amdgcn_cvt_f32_fp8(w, 1) * inv2);
    float e2 = exp2f(__builtin_amdgcn_cvt_f32_fp8(w, 2) * inv2);
    float e3 = exp2f(__builtin_amdgcn_cvt_f32_fp8(w, 3) * inv2);
    dsum += e0 + e1 + e2 + e3;
    nsum += e0 * (float)yv.x + e1 * (float)yv.y + e2 * (float)yv.z +
            e3 * (float)yv.w;
  }
  atomicAdd(&denom[b], dsum);
  atomicAdd(&numer[src * Bdim + b], nsum);
}

// ---------------------------------------------------------------------------
// Kernel 4 (tiny): out[b] = sigmoid(sum_s numer[s,b]*theta[s,b]/denom[b]+bias)
// ---------------------------------------------------------------------------
__global__ void finalize_kernel(const float* __restrict__ denom,
                                const float* __restrict__ numer,
                                const float* __restrict__ theta,
                                const float* __restrict__ bias,
                                float* __restrict__ out) {
  int b = blockIdx.x * 256 + threadIdx.x;
  float acc = 0.f;
#pragma unroll
  for (int si = 0; si < Sdim; ++si)
    acc += numer[si * Bdim + b] * theta[si * Bdim + b];
  float z = acc / denom[b] + bias[0];
  out[b] = 1.0f / (1.0f + __expf(-z));
}

// ---------------------------------------------------------------------------
// Workspace layout (bytes):
//   catq  : Ndim*Ddim     =  6,291,456   (fp8)
//   xq    : Bdim*Ddim     =  3,145,728   (fp8)
//   conq  : Ndim*Bdim     = 33,554,432   (fp8, [N/4, B, 4] interleaved)
//   stats : 6*Bdim*4      =     98,304   (s4 | denom | numer)
//   theta : Sdim*Bdim*4   =     65,536
//   total ≈ 43.2 MB
// Session ledger (GEMM µs, measured): gl_lds single 58.9 (R17/R19) ≈
// reg-prefetch 59.2 (R20) < gl_lds dbuf 66.6 (R14) < spill 79.6/161.
// Non-GEMM ~96 µs: kernels ~20 (near BW floors) + ~76 fixed harness/reset
// overhead (not addressable from kernel_launch).
// ---------------------------------------------------------------------------
extern "C" void kernel_launch(void* const* d_in, const int* in_sizes, int n_in,
                              void* d_out, int out_size, void* d_ws,
                              size_t ws_size, hipStream_t stream) {
  const float* batch_x = (const float*)d_in[0];
  const float* cat = (const float*)d_in[1];
  const int* y = (const int*)d_in[2];
  const float* phi = (const float*)d_in[3];
  const float* bias = (const float*)d_in[4];
  float* out = (float*)d_out;

  char* ws = (char*)d_ws;
  unsigned char* catq = (unsigned char*)ws;
  unsigned char* xq = catq + (size_t)Ndim * Ddim;
  unsigned int* conq = (unsigned int*)(xq + (size_t)Bdim * Ddim);
  float* stats = (float*)((unsigned char*)conq + (size_t)Ndim * Bdim);
  float* s4 = stats;
  float* denom = s4 + Bdim;
  float* numer = denom + Bdim;        // Sdim * Bdim
  float* theta = stats + 6 * Bdim;    // Sdim * Bdim

  convert_kernel<<<2048, 256, 0, stream>>>(batch_x, cat, phi, xq, catq, stats,
                                           theta);

  dim3 g2(Ndim / 128, Bdim / 128);
  gemm_bt_kernel<<<g2, 256, 0, stream>>>(catq, xq, conq, s4);

  dim3 g3(Bdim / 256, 128);
  expsum_kernel<<<g3, 256, 0, stream>>>(conq, s4, y, denom, numer);

  finalize_kernel<<<Bdim / 256, 256, 0, stream>>>(denom, numer, theta, bias,
                                                  out);
}